// Round 5
// baseline (992.057 us; speedup 1.0000x reference)
//
#include <hip/hip_runtime.h>

#define BB 4
#define NN 1024
#define KK 100
#define TT 2
#define HH 64
#define FF 96

// d_out layout (floats): Etot [0,4) | Ei [4,4100) | Force [4100,16388) | Virial [16388,16424)
#define OFF_EI   4
#define OFF_F    (4 + BB*NN)
#define OFF_VIR  (OFF_F + BB*NN*3)
#define OUT_TOT  (OFF_VIR + BB*9)

// d_ws layout (floats): W1T [T][H][F] | W2T [T][H][H]
#define WS_W1T   0
#define WS_W2T   (TT*HH*FF)
#define PREP_MAX ((OUT_TOT > TT*FF*HH) ? OUT_TOT : TT*FF*HH)

#define NPASS    ((KK + 15) / 16)   // 7 passes of 16 pairs

__device__ __forceinline__ float wave_sum(float v) {
    #pragma unroll
    for (int off = 32; off > 0; off >>= 1)
        v += __shfl_xor(v, off, 64);
    return v;
}

// Zero d_out accumulators AND build transposed weights in one launch.
__global__ __launch_bounds__(256) void prep_kernel(
    const float* __restrict__ W1, const float* __restrict__ W2,
    float* __restrict__ ws, float* __restrict__ out)
{
    int i = blockIdx.x * 256 + threadIdx.x;
    if (i < OUT_TOT) out[i] = 0.f;
    float* W1T = ws + WS_W1T;   // [T][H][F]
    float* W2T = ws + WS_W2T;   // [T][H][H]  (W2T[t][g][h] = W2[t][h][g])
    if (i < TT * FF * HH) {
        int t = i / (FF * HH), r = i % (FF * HH);
        int f = r / HH, h = r % HH;
        W1T[(t * HH + h) * FF + f] = W1[i];
    }
    if (i < TT * HH * HH) {
        int t = i / (HH * HH), r = i % (HH * HH);
        int h = r / HH, g = r % HH;
        W2T[(t * HH + g) * HH + h] = W2[i];
    }
}

// One WAVE per (b,n) row; 4 rows per 256-thread block.
// Phase 1: each wave runs its row's MLP fwd+VJP (lane = hidden unit),
//          writes dE[96] to its private LDS slice.  One __syncthreads.
// Phase 2: lanes-as-pairs. lane = 4*g+q; group g owns pair k = pass*16+g;
//          lane q covers features f = it*4+q (float3 loads, 48B/group/instr).
//          Depth-2 shuffle reduce per pair; scatter atomics from q==0 lanes.
__global__ __launch_bounds__(256) void fused_kernel(
    const float* __restrict__ feat, const int* __restrict__ tmap,
    const float* __restrict__ W1, const float* __restrict__ b1,
    const float* __restrict__ W2, const float* __restrict__ b2,
    const float* __restrict__ rdt, const float* __restrict__ Wout,
    const float* __restrict__ bout, const float* __restrict__ ws,
    const float* __restrict__ dfeat, const float* __restrict__ ImageDR,
    const int* __restrict__ neigh, float* __restrict__ out)
{
    const int tid  = threadIdx.x;
    const int wave = tid >> 6;
    const int lane = tid & 63;
    const int row  = blockIdx.x * 4 + wave;     // b*NN + n
    const int b    = row >> 10;                 // row / NN
    const int n    = row & (NN - 1);

    __shared__ float sdE[4][FF];

    // ---- Phase 1: MLP forward + VJP (this wave's row), in registers ----
    {
        const int t = tmap[n];
        const float* frow = feat + (size_t)row * FF;
        const float* W1t  = W1 + (size_t)t * FF * HH;
        const float* W2t  = W2 + (size_t)t * HH * HH;
        const float* W1Tt = ws + WS_W1T + (size_t)t * HH * FF;
        const float* W2Tt = ws + WS_W2T + (size_t)t * HH * HH;

        float f0 = frow[lane];
        float f1 = (lane < 32) ? frow[HH + lane] : 0.f;

        float z1 = b1[t * HH + lane];
        #pragma unroll 8
        for (int f = 0; f < HH; ++f)
            z1 = fmaf(__shfl(f0, f, 64), W1t[f * HH + lane], z1);
        #pragma unroll 8
        for (int f = 0; f < FF - HH; ++f)
            z1 = fmaf(__shfl(f1, f, 64), W1t[(HH + f) * HH + lane], z1);
        float h1 = tanhf(z1);

        float z2 = b2[t * HH + lane];
        #pragma unroll 8
        for (int h = 0; h < HH; ++h)
            z2 = fmaf(__shfl(h1, h, 64), W2t[h * HH + lane], z2);
        float u  = tanhf(z2);
        float r  = rdt[t * HH + lane];
        float wo = Wout[t * HH + lane];

        float e = wave_sum((h1 + r * u) * wo);

        float dz2 = r * wo * (1.f - u * u);
        float dh1 = wo;
        #pragma unroll 8
        for (int g = 0; g < HH; ++g)
            dh1 = fmaf(__shfl(dz2, g, 64), W2Tt[g * HH + lane], dh1);
        float dz1 = dh1 * (1.f - h1 * h1);

        float w0 = 0.f, w1 = 0.f;   // dE[lane], dE[64+lane]
        #pragma unroll 8
        for (int h = 0; h < HH; ++h) {
            const float d = __shfl(dz1, h, 64);
            w0 = fmaf(d, W1Tt[h * FF + lane], w0);
            if (lane < 32) w1 = fmaf(d, W1Tt[h * FF + HH + lane], w1);
        }

        sdE[wave][lane] = w0;
        if (lane < 32) sdE[wave][HH + lane] = w1;

        if (lane == 0) {
            const float Ei = e + bout[t];
            out[OFF_EI + row] = Ei;
            atomicAdd(&out[b], Ei);
        }
    }
    __syncthreads();

    // ---- Phase 2: pair contraction, lanes-as-pairs ----
    const int g = lane >> 2;        // pair group 0..15
    const int q = lane & 3;         // feature sub-lane
    const float* sd = sdE[wave];
    const size_t rowPair = (size_t)row * KK;

    // prefetch neighbor indices for all passes (coalesced, hides latency)
    int jv[NPASS];
    #pragma unroll
    for (int p = 0; p < NPASS; ++p) {
        const int k = p * 16 + g;
        jv[p] = (k < KK) ? neigh[rowPair + k] : 0;
    }

    float ssum0 = 0.f, ssum1 = 0.f, ssum2 = 0.f;  // sum_k pair_f (valid only)
    float vir[9] = {0.f,0.f,0.f,0.f,0.f,0.f,0.f,0.f,0.f};

    for (int p = 0; p < NPASS; ++p) {
        const int k = p * 16 + g;
        const bool act = (k < KK);
        float a0 = 0.f, a1 = 0.f, a2 = 0.f;
        if (act) {
            const float* dfp = dfeat + (rowPair + k) * (FF * 3);
            #pragma unroll
            for (int it = 0; it < FF / 4; ++it) {
                const int f = it * 4 + q;
                const float d = sd[f];
                const float3 v = *(const float3*)(dfp + f * 3);
                a0 = fmaf(v.x, d, a0);
                a1 = fmaf(v.y, d, a1);
                a2 = fmaf(v.z, d, a2);
            }
        }
        // reduce over the 4-lane feature group
        a0 += __shfl_xor(a0, 1, 64); a0 += __shfl_xor(a0, 2, 64);
        a1 += __shfl_xor(a1, 1, 64); a1 += __shfl_xor(a1, 2, 64);
        a2 += __shfl_xor(a2, 1, 64); a2 += __shfl_xor(a2, 2, 64);

        if (act && q == 0) {
            const int j = jv[p];
            if (j > 0) {
                const float* drp = ImageDR + (rowPair + k) * 4;
                const float rx = drp[1], ry = drp[2], rz = drp[3];
                atomicAdd(&out[OFF_F + ((size_t)b * NN + (j - 1)) * 3 + 0], a0);
                atomicAdd(&out[OFF_F + ((size_t)b * NN + (j - 1)) * 3 + 1], a1);
                atomicAdd(&out[OFF_F + ((size_t)b * NN + (j - 1)) * 3 + 2], a2);
                ssum0 += a0; ssum1 += a1; ssum2 += a2;
                vir[0] = fmaf(rx, a0, vir[0]);
                vir[1] = fmaf(rx, a1, vir[1]);
                vir[2] = fmaf(rx, a2, vir[2]);
                vir[3] = fmaf(ry, a0, vir[3]);
                vir[4] = fmaf(ry, a1, vir[4]);
                vir[5] = fmaf(ry, a2, vir[5]);
                vir[6] = fmaf(rz, a0, vir[6]);
                vir[7] = fmaf(rz, a1, vir[7]);
                vir[8] = fmaf(rz, a2, vir[8]);
            }
        }
    }

    // wave-level reduction of self-force + virial, one set of atomics per row
    const float S0 = wave_sum(ssum0);
    const float S1 = wave_sum(ssum1);
    const float S2 = wave_sum(ssum2);
    #pragma unroll
    for (int i = 0; i < 9; ++i) vir[i] = wave_sum(vir[i]);

    if (lane == 0) {
        atomicAdd(&out[OFF_F + (size_t)row * 3 + 0], -S0);
        atomicAdd(&out[OFF_F + (size_t)row * 3 + 1], -S1);
        atomicAdd(&out[OFF_F + (size_t)row * 3 + 2], -S2);
        #pragma unroll
        for (int i = 0; i < 9; ++i)
            atomicAdd(&out[OFF_VIR + b * 9 + i], -vir[i]);
    }
}

extern "C" void kernel_launch(void* const* d_in, const int* in_sizes, int n_in,
                              void* d_out, int out_size, void* d_ws, size_t ws_size,
                              hipStream_t stream) {
    const float* feat    = (const float*)d_in[0];
    const float* dfeat   = (const float*)d_in[1];
    const float* ImageDR = (const float*)d_in[2];
    const int*   neigh   = (const int*)  d_in[3];
    const int*   tmap    = (const int*)  d_in[4];
    const float* W1      = (const float*)d_in[5];
    const float* b1      = (const float*)d_in[6];
    const float* W2      = (const float*)d_in[7];
    const float* b2      = (const float*)d_in[8];
    const float* rdt     = (const float*)d_in[9];
    const float* Wout    = (const float*)d_in[10];
    const float* bout    = (const float*)d_in[11];

    float* out = (float*)d_out;
    float* ws  = (float*)d_ws;

    prep_kernel<<<(PREP_MAX + 255) / 256, 256, 0, stream>>>(W1, W2, ws, out);
    fused_kernel<<<BB * NN / 4, 256, 0, stream>>>(feat, tmap, W1, b1, W2, b2,
                                                  rdt, Wout, bout, ws, dfeat,
                                                  ImageDR, neigh, out);
}